// Round 2
// baseline (66.069 us; speedup 1.0000x reference)
//
#include <hip/hip_runtime.h>
#include <math.h>

// ---- Problem constants (from reference) ----
#define KPT 9
#define NB 16
#define NH 76
#define NW 76
#define MAX_T 50
#define NCH 20                 // NA*(2K+1+NC) = 20
#define NUM_LABELS 21          // 2K+3
#define CELLS (NH*NW)          // 5776
#define IM_W 640.0f
#define IM_H 480.0f
#define DIST_THRESH 30.0f
#define SIL_THRESH 0.6f
#define OBJECT_SCALE 5.0f
#define NOOBJECT_SCALE 0.1f
#define PRETRAIN_EPOCHS 15
// c = (exp(2*(1-d/30)) - 1) / (e^2 - 1), mean over K=9
// CNORM folds the /(e^2-1)/9 normalization applied to the raw sum.
#define E2M1 5.3890560989306495f
#define CNORM (1.0f/(E2M1*9.0f))
// curconf > SIL_THRESH  <=>  raw csum max > SIL_THRESH/CNORM
#define CURMAX_BREAK (SIL_THRESH * E2M1 * 9.0f)

__device__ __forceinline__ float sigmoidf_(float x) {
    return 1.0f / (1.0f + __expf(-x));
}

__global__ void zero_out_kernel(float* d_out) {
    d_out[0] = 0.0f;
}

__launch_bounds__(256)
__global__ void region_loss_kernel(const float* __restrict__ output,
                                   const float* __restrict__ target,
                                   const int* __restrict__ epoch_p,
                                   float* __restrict__ d_out)
{
    const int tid = threadIdx.x;
    const int b = blockIdx.y;

    __shared__ float s_gtx[MAX_T][KPT];   // gt x in pixels (×640)
    __shared__ float s_gty[MAX_T][KPT];   // gt y in pixels (×480)
    __shared__ float s_tx[MAX_T][KPT];    // tx_vals = gx*NW - gi0
    __shared__ float s_ty[MAX_T][KPT];    // ty_vals = gy*NH - gj0
    __shared__ float4 s_bb[MAX_T];        // {minx-30, maxx+30, miny-30, maxy+30} px
    __shared__ float s_tconf[MAX_T];
    __shared__ int   s_cell[MAX_T];       // scatter cell or -1
    __shared__ int   s_nvalid;
    __shared__ float s_red[256];

    const float* tgb = target + (size_t)b * MAX_T * NUM_LABELS;

    // ---- validity prefix (cumprod of tgt[:,:,1] != 0) via wave-0 ballot ----
    if (tid < 64) {
        float v1 = (tid < MAX_T) ? tgb[tid * NUM_LABELS + 1] : 1.0f;
        unsigned long long zm = __ballot(v1 == 0.0f);
        if (tid == 0) {
            int fz = (zm == 0ULL) ? MAX_T : (__ffsll((long long)zm) - 1);
            s_nvalid = fz < MAX_T ? fz : MAX_T;
        }
    }

    // ---- per-target precompute into LDS (threads 0..49) ----
    if (tid < MAX_T) {
        const float* row = tgb + tid * NUM_LABELS;
        float gx0 = row[1] * (float)NW;
        float gy0 = row[2] * (float)NH;
        int gi0 = (int)gx0;               // truncation == astype(int32)
        int gj0 = (int)gy0;
        int cellt = gj0 * NW + gi0;
        int cellc = min(max(cellt, 0), CELLS - 1);
        int hc = cellc / NW, wc = cellc % NW;
        const float* ob = output + (size_t)b * NCH * CELLS + cellc;
        float csum = 0.0f;
        float mnx = 1e9f, mxx = -1e9f, mny = 1e9f, mxy = -1e9f;
        #pragma unroll
        for (int k = 0; k < KPT; ++k) {
            float gxk = row[1 + 2*k];
            float gyk = row[2 + 2*k];
            float gxp = gxk * IM_W;
            float gyp = gyk * IM_H;
            s_gtx[tid][k] = gxp;
            s_gty[tid][k] = gyp;
            mnx = fminf(mnx, gxp); mxx = fmaxf(mxx, gxp);
            mny = fminf(mny, gyp); mxy = fmaxf(mxy, gyp);
            s_tx[tid][k]  = gxk * (float)NW - (float)gi0;
            s_ty[tid][k]  = gyk * (float)NH - (float)gj0;
            float xo = ob[(2*k) * CELLS];
            float yo = ob[(2*k + 1) * CELLS];
            if (k == 0) { xo = sigmoidf_(xo); yo = sigmoidf_(yo); }
            float pxs = (xo + (float)wc) * (IM_W / (float)NW);
            float pys = (yo + (float)hc) * (IM_H / (float)NH);
            float dx = gxp - pxs;
            float dy = gyp - pys;
            float d2 = dx*dx + dy*dy;
            if (d2 < DIST_THRESH * DIST_THRESH) {
                csum += __expf(2.0f - sqrtf(d2) * (2.0f / DIST_THRESH)) - 1.0f;
            }
        }
        s_tconf[tid] = csum * CNORM;
        s_cell[tid] = (gi0 >= 0 && gi0 < NW && gj0 >= 0 && gj0 < NH) ? cellt : -1;
        s_bb[tid] = make_float4(mnx - DIST_THRESH, mxx + DIST_THRESH,
                                mny - DIST_THRESH, mxy + DIST_THRESH);
    }
    __syncthreads();

    const int epoch = epoch_p[0];
    const int nv = s_nvalid;
    const int cell = blockIdx.x * blockDim.x + tid;
    float contrib = 0.0f;

    if (cell < CELLS) {
        const int h = cell / NW;
        const int w = cell - h * NW;
        const float* ob = output + (size_t)b * NCH * CELLS + cell;

        float xs[KPT], ys[KPT], pxs[KPT], pys[KPT];
        float pminx = 1e9f, pmaxx = -1e9f, pminy = 1e9f, pmaxy = -1e9f;
        #pragma unroll
        for (int k = 0; k < KPT; ++k) {
            float xo = ob[(2*k) * CELLS];
            float yo = ob[(2*k + 1) * CELLS];
            if (k == 0) { xo = sigmoidf_(xo); yo = sigmoidf_(yo); }
            xs[k] = xo; ys[k] = yo;
            float px = (xo + (float)w) * (IM_W / (float)NW);
            float py = (yo + (float)h) * (IM_H / (float)NH);
            pxs[k] = px; pys[k] = py;
            pminx = fminf(pminx, px); pmaxx = fmaxf(pmaxx, px);
            pminy = fminf(pminy, py); pmaxy = fmaxf(pmaxy, py);
        }
        const float conf = sigmoidf_(ob[2*KPT * CELLS]);

        // ---- winner search (last valid t with s_cell==cell wins, scatter order) ----
        int winner = -1;
        for (int t = 0; t < nv; ++t) {
            if (s_cell[t] == cell) winner = t;   // LDS broadcast, cheap
        }

        float cmask, tconf;
        if (winner >= 0) {
            // curmax irrelevant: cmask is OBJECT_SCALE regardless
            cmask = OBJECT_SCALE;
            tconf = s_tconf[winner];
            #pragma unroll
            for (int k = 0; k < KPT; ++k) {
                float dxv = xs[k] - s_tx[winner][k];
                float dyv = ys[k] - s_ty[winner][k];
                contrib += 0.5f * (dxv*dxv + dyv*dyv);   // COORD_SCALE = 1
            }
        } else {
            // only need boolean: max csum > CURMAX_BREAK ?
            float curmax = 0.0f;
            for (int t = 0; t < nv; ++t) {
                float4 bb = s_bb[t];
                // bbox overlap reject: can any keypoint be within 30px?
                if (pmaxx >= bb.x && pminx <= bb.y && pmaxy >= bb.z && pminy <= bb.w) {
                    float csum = 0.0f;
                    #pragma unroll
                    for (int k = 0; k < KPT; ++k) {
                        float dx = s_gtx[t][k] - pxs[k];
                        float dy = s_gty[t][k] - pys[k];
                        float d2 = dx*dx + dy*dy;
                        if (d2 < DIST_THRESH * DIST_THRESH) {
                            csum += __expf(2.0f - sqrtf(d2) * (2.0f / DIST_THRESH)) - 1.0f;
                        }
                    }
                    curmax = fmaxf(curmax, csum);
                    if (curmax > CURMAX_BREAK) break;   // boolean is monotone
                }
            }
            cmask = (curmax > CURMAX_BREAK) ? 0.0f : NOOBJECT_SCALE;
            tconf = 0.0f;
        }
        if (epoch > PRETRAIN_EPOCHS) {
            float d = conf - tconf;
            contrib += 0.5f * cmask * d * d;
        }
    }

    // ---- block reduction + one atomic per block ----
    s_red[tid] = contrib;
    __syncthreads();
    for (int s = 128; s > 0; s >>= 1) {
        if (tid < s) s_red[tid] += s_red[tid + s];
        __syncthreads();
    }
    if (tid == 0) atomicAdd(d_out, s_red[0]);
}

extern "C" void kernel_launch(void* const* d_in, const int* in_sizes, int n_in,
                              void* d_out, int out_size, void* d_ws, size_t ws_size,
                              hipStream_t stream) {
    const float* output = (const float*)d_in[0];
    const float* target = (const float*)d_in[1];
    const int*   epoch  = (const int*)d_in[2];
    float* out = (float*)d_out;

    zero_out_kernel<<<1, 1, 0, stream>>>(out);

    dim3 grid((CELLS + 255) / 256, NB);
    region_loss_kernel<<<grid, 256, 0, stream>>>(output, target, epoch, out);
}

// Round 3
// 48.844 us; speedup vs baseline: 1.3527x; 1.3527x over previous
//
#include <hip/hip_runtime.h>
#include <math.h>

// ---- Problem constants (from reference) ----
#define KPT 9
#define NB 16
#define NH 76
#define NW 76
#define MAX_T 50
#define NCH 20                 // NA*(2K+1+NC) = 20
#define NUM_LABELS 21          // 2K+3
#define CELLS (NH*NW)          // 5776
#define IM_W 640.0f
#define IM_H 480.0f
#define SX (IM_W/(float)NW)    // px per cell, x
#define SY (IM_H/(float)NH)    // px per cell, y
#define DIST_THRESH 30.0f
#define SIL_THRESH 0.6f
#define OBJECT_SCALE 5.0f
#define NOOBJECT_SCALE 0.1f
#define PRETRAIN_EPOCHS 15
// c = (exp(2*(1-d/30)) - 1) / (e^2 - 1), mean over K=9
#define E2M1 5.3890560989306495f
#define CNORM (1.0f/(E2M1*9.0f))

#define TSPLIT 4               // target-loop split across 4 waves
#define CPB 64                 // cells per block (one per lane)

__device__ __forceinline__ float sigmoidf_(float x) {
    return 1.0f / (1.0f + __expf(-x));
}

__global__ void zero_out_kernel(float* d_out) {
    d_out[0] = 0.0f;
}

__launch_bounds__(256)
__global__ void region_loss_kernel(const float* __restrict__ output,
                                   const float* __restrict__ target,
                                   const int* __restrict__ epoch_p,
                                   float* __restrict__ d_out)
{
    const int tid  = threadIdx.x;
    const int wave = tid >> 6;       // 0..3 = target chunk
    const int cl   = tid & 63;       // cell within block
    const int b    = blockIdx.y;
    const int cell = blockIdx.x * CPB + cl;
    const bool live = (cell < CELLS);

    __shared__ float2 s_gt[MAX_T][KPT];    // gt coords in pixels
    __shared__ float2 s_txy[MAX_T][KPT];   // (tx,ty) residual targets
    __shared__ float  s_tconf[MAX_T];
    __shared__ int    s_cell[MAX_T];       // scatter cell or -1
    __shared__ int    s_nvalid;
    __shared__ float  s_cmax[TSPLIT][CPB];
    __shared__ int    s_winp[TSPLIT][CPB];

    const float* tgb = target + (size_t)b * MAX_T * NUM_LABELS;

    // ---- validity prefix (cumprod of tgt[:,:,1] != 0) via wave-0 ballot ----
    if (tid < 64) {
        float v1 = (tid < MAX_T) ? tgb[tid * NUM_LABELS + 1] : 1.0f;
        unsigned long long zm = __ballot(v1 == 0.0f);
        if (tid == 0) {
            int fz = (zm == 0ULL) ? MAX_T : (__ffsll((long long)zm) - 1);
            s_nvalid = fz < MAX_T ? fz : MAX_T;
        }
    }

    // ---- per-target precompute into LDS (threads 0..49) ----
    if (tid < MAX_T) {
        const float* row = tgb + tid * NUM_LABELS;
        float gx0 = row[1] * (float)NW;
        float gy0 = row[2] * (float)NH;
        int gi0 = (int)gx0;               // truncation == astype(int32)
        int gj0 = (int)gy0;
        int cellt = gj0 * NW + gi0;
        int cellc = min(max(cellt, 0), CELLS - 1);
        int hc = cellc / NW, wc = cellc % NW;
        const float* ob = output + (size_t)b * NCH * CELLS + cellc;
        float csum = 0.0f;
        #pragma unroll
        for (int k = 0; k < KPT; ++k) {
            float gxk = row[1 + 2*k];
            float gyk = row[2 + 2*k];
            float gxp = gxk * IM_W;
            float gyp = gyk * IM_H;
            s_gt[tid][k]  = make_float2(gxp, gyp);
            s_txy[tid][k] = make_float2(gxk * (float)NW - (float)gi0,
                                        gyk * (float)NH - (float)gj0);
            float xo = ob[(2*k) * CELLS];
            float yo = ob[(2*k + 1) * CELLS];
            if (k == 0) { xo = sigmoidf_(xo); yo = sigmoidf_(yo); }
            float dx = gxp - (xo + (float)wc) * SX;
            float dy = gyp - (yo + (float)hc) * SY;
            float d2 = dx*dx + dy*dy;
            if (d2 < DIST_THRESH * DIST_THRESH) {
                csum += __expf(2.0f - sqrtf(d2) * (2.0f / DIST_THRESH)) - 1.0f;
            }
        }
        s_tconf[tid] = csum * CNORM;
        s_cell[tid] = (gi0 >= 0 && gi0 < NW && gj0 >= 0 && gj0 < NH) ? cellt : -1;
    }
    __syncthreads();

    const int nv = s_nvalid;

    // ---- phase 1: each wave scans its strided target chunk ----
    float pxs[KPT], pys[KPT];
    float curmax = 0.0f;
    int   win = -1;
    if (live) {
        const int h = cell / NW;
        const int w = cell - h * NW;
        const float* ob = output + (size_t)b * NCH * CELLS + cell;
        #pragma unroll
        for (int k = 0; k < KPT; ++k) {
            float xo = ob[(2*k) * CELLS];
            float yo = ob[(2*k + 1) * CELLS];
            if (k == 0) { xo = sigmoidf_(xo); yo = sigmoidf_(yo); }
            pxs[k] = (xo + (float)w) * SX;
            pys[k] = (yo + (float)h) * SY;
        }
        for (int t = wave; t < nv; t += TSPLIT) {
            float csum = 0.0f;
            #pragma unroll
            for (int k = 0; k < KPT; ++k) {
                float2 g = s_gt[t][k];           // broadcast read, no conflict
                float dx = g.x - pxs[k];
                float dy = g.y - pys[k];
                float d2 = __builtin_fmaf(dx, dx, dy*dy);
                if (d2 < DIST_THRESH * DIST_THRESH) {
                    csum += __expf(2.0f - sqrtf(d2) * (2.0f / DIST_THRESH)) - 1.0f;
                }
            }
            curmax = fmaxf(curmax, csum);
            if (s_cell[t] == cell) win = t;      // last valid t wins
        }
    }
    s_cmax[wave][cl] = curmax;
    s_winp[wave][cl] = win;
    __syncthreads();

    // ---- phase 2: wave 0 combines chunks + computes the loss ----
    float contrib = 0.0f;
    if (wave == 0 && live) {
        float cm = fmaxf(fmaxf(s_cmax[0][cl], s_cmax[1][cl]),
                         fmaxf(s_cmax[2][cl], s_cmax[3][cl]));
        int wn = max(max(s_winp[0][cl], s_winp[1][cl]),
                     max(s_winp[2][cl], s_winp[3][cl]));
        const int h = cell / NW;
        const int w = cell - h * NW;
        const float* ob = output + (size_t)b * NCH * CELLS + cell;
        const float conf = sigmoidf_(ob[2*KPT * CELLS]);

        float cmask, tconf;
        if (wn >= 0) {
            cmask = OBJECT_SCALE;
            tconf = s_tconf[wn];
            #pragma unroll
            for (int k = 0; k < KPT; ++k) {
                // recover raw (xs,ys) from pixel preds: xo = px/SX - w
                float xo = pxs[k] * (1.0f/SX) - (float)w;
                float yo = pys[k] * (1.0f/SY) - (float)h;
                float2 txy = s_txy[wn][k];
                float dxv = xo - txy.x;
                float dyv = yo - txy.y;
                contrib += 0.5f * (dxv*dxv + dyv*dyv);   // COORD_SCALE = 1
            }
        } else {
            cmask = (cm * CNORM > SIL_THRESH) ? 0.0f : NOOBJECT_SCALE;
            tconf = 0.0f;
        }
        if (epoch_p[0] > PRETRAIN_EPOCHS) {
            float d = conf - tconf;
            contrib += 0.5f * cmask * d * d;
        }
    }

    // ---- wave-0 shuffle reduction + one atomic per block ----
    if (wave == 0) {
        #pragma unroll
        for (int off = 32; off > 0; off >>= 1)
            contrib += __shfl_down(contrib, off);
        if (cl == 0) atomicAdd(d_out, contrib);
    }
}

extern "C" void kernel_launch(void* const* d_in, const int* in_sizes, int n_in,
                              void* d_out, int out_size, void* d_ws, size_t ws_size,
                              hipStream_t stream) {
    const float* output = (const float*)d_in[0];
    const float* target = (const float*)d_in[1];
    const int*   epoch  = (const int*)d_in[2];
    float* out = (float*)d_out;

    zero_out_kernel<<<1, 1, 0, stream>>>(out);

    dim3 grid((CELLS + CPB - 1) / CPB, NB);
    region_loss_kernel<<<grid, 256, 0, stream>>>(output, target, epoch, out);
}

// Round 4
// 37.879 us; speedup vs baseline: 1.7442x; 1.2895x over previous
//
#include <hip/hip_runtime.h>
#include <math.h>

// ---- Problem constants (from reference) ----
#define KPT 9
#define NB 16
#define NH 76
#define NW 76
#define MAX_T 50
#define NCH 20                 // NA*(2K+1+NC) = 20
#define NUM_LABELS 21          // 2K+3
#define CELLS (NH*NW)          // 5776
#define IM_W 640.0f
#define IM_H 480.0f
#define SX (IM_W/(float)NW)    // px per cell, x
#define SY (IM_H/(float)NH)    // px per cell, y
#define DIST_THRESH 30.0f
#define D2_THRESH (DIST_THRESH*DIST_THRESH)
#define SIL_THRESH 0.6f
#define OBJECT_SCALE 5.0f
#define NOOBJECT_SCALE 0.1f
#define PRETRAIN_EPOCHS 15
// c = (exp(2*(1-d/30)) - 1) / (e^2 - 1), mean over K=9
#define E2M1 6.3890560989306495f          // e^2 - 1 (was e^2-2: fixed)
#define CNORM (1.0f/(E2M1*9.0f))
// curconf > SIL_THRESH  <=>  raw csum > SIL_THRESH*(e^2-1)*9
#define CURMAX_BREAK (SIL_THRESH * E2M1 * 9.0f)
// csum <= cnt_close * (e^2-1); csum > BREAK requires cnt_close >= 6
#define CNT_MIN 6

#define TSPLIT 4               // target-loop split across 4 waves
#define CPB 64                 // cells per block (one per lane)

__device__ __forceinline__ float sigmoidf_(float x) {
    return 1.0f / (1.0f + __expf(-x));
}

__global__ void zero_out_kernel(float* d_out) {
    d_out[0] = 0.0f;
}

__launch_bounds__(256)
__global__ void region_loss_kernel(const float* __restrict__ output,
                                   const float* __restrict__ target,
                                   const int* __restrict__ epoch_p,
                                   float* __restrict__ d_out)
{
    const int tid  = threadIdx.x;
    const int wave = tid >> 6;       // 0..3 = target chunk
    const int cl   = tid & 63;       // cell within block
    const int b    = blockIdx.y;
    const int cell = blockIdx.x * CPB + cl;
    const bool live = (cell < CELLS);

    __shared__ float2 s_gt[MAX_T][KPT];    // gt coords in pixels
    __shared__ float2 s_txy[MAX_T][KPT];   // (tx,ty) residual targets
    __shared__ float  s_tconf[MAX_T];
    __shared__ int    s_cell[MAX_T];       // scatter cell or -1
    __shared__ int    s_nvalid;
    __shared__ float  s_sil[TSPLIT][CPB];  // 1.0 if any t in chunk silences cell
    __shared__ int    s_winp[TSPLIT][CPB];

    const float* tgb = target + (size_t)b * MAX_T * NUM_LABELS;

    // ---- validity prefix (cumprod of tgt[:,:,1] != 0) via wave-0 ballot ----
    if (tid < 64) {
        float v1 = (tid < MAX_T) ? tgb[tid * NUM_LABELS + 1] : 1.0f;
        unsigned long long zm = __ballot(v1 == 0.0f);
        if (tid == 0) {
            int fz = (zm == 0ULL) ? MAX_T : (__ffsll((long long)zm) - 1);
            s_nvalid = fz < MAX_T ? fz : MAX_T;
        }
    }

    // ---- per-target precompute into LDS (threads 0..49) ----
    if (tid < MAX_T) {
        const float* row = tgb + tid * NUM_LABELS;
        float gx0 = row[1] * (float)NW;
        float gy0 = row[2] * (float)NH;
        int gi0 = (int)gx0;               // truncation == astype(int32)
        int gj0 = (int)gy0;
        int cellt = gj0 * NW + gi0;
        int cellc = min(max(cellt, 0), CELLS - 1);
        int hc = cellc / NW, wc = cellc % NW;
        const float* ob = output + (size_t)b * NCH * CELLS + cellc;
        float csum = 0.0f;
        #pragma unroll
        for (int k = 0; k < KPT; ++k) {
            float gxk = row[1 + 2*k];
            float gyk = row[2 + 2*k];
            float gxp = gxk * IM_W;
            float gyp = gyk * IM_H;
            s_gt[tid][k]  = make_float2(gxp, gyp);
            s_txy[tid][k] = make_float2(gxk * (float)NW - (float)gi0,
                                        gyk * (float)NH - (float)gj0);
            float xo = ob[(2*k) * CELLS];
            float yo = ob[(2*k + 1) * CELLS];
            if (k == 0) { xo = sigmoidf_(xo); yo = sigmoidf_(yo); }
            float dx = gxp - (xo + (float)wc) * SX;
            float dy = gyp - (yo + (float)hc) * SY;
            float d2 = dx*dx + dy*dy;
            if (d2 < D2_THRESH) {
                csum += __expf(2.0f - sqrtf(d2) * (2.0f / DIST_THRESH)) - 1.0f;
            }
        }
        s_tconf[tid] = csum * CNORM;
        s_cell[tid] = (gi0 >= 0 && gi0 < NW && gj0 >= 0 && gj0 < NH) ? cellt : -1;
    }
    __syncthreads();

    const int nv = s_nvalid;

    // ---- phase 1: each wave scans its strided target chunk (branchless) ----
    float pxs[KPT], pys[KPT];
    float sil = 0.0f;                // cell silenced (curconf > SIL_THRESH)?
    int   win = -1;
    if (live) {
        const int h = cell / NW;
        const int w = cell - h * NW;
        const float* ob = output + (size_t)b * NCH * CELLS + cell;
        #pragma unroll
        for (int k = 0; k < KPT; ++k) {
            float xo = ob[(2*k) * CELLS];
            float yo = ob[(2*k + 1) * CELLS];
            if (k == 0) { xo = sigmoidf_(xo); yo = sigmoidf_(yo); }
            pxs[k] = (xo + (float)w) * SX;
            pys[k] = (yo + (float)h) * SY;
        }
        for (int t = wave; t < nv; t += TSPLIT) {
            int cnt = 0;
            #pragma unroll
            for (int k = 0; k < KPT; ++k) {
                float2 g = s_gt[t][k];           // broadcast read, no conflict
                float dx = g.x - pxs[k];
                float dy = g.y - pys[k];
                float d2 = __builtin_fmaf(dx, dx, dy*dy);
                cnt += (d2 < D2_THRESH) ? 1 : 0; // branchless close-count
            }
            // csum can exceed CURMAX_BREAK only if >= CNT_MIN keypoints close.
            // Exec-masked rare path (P ~ 1e-10 per pair): exact evaluation.
            if (cnt >= CNT_MIN) {
                float csum = 0.0f;
                #pragma unroll
                for (int k = 0; k < KPT; ++k) {
                    float2 g = s_gt[t][k];
                    float dx = g.x - pxs[k];
                    float dy = g.y - pys[k];
                    float d2 = __builtin_fmaf(dx, dx, dy*dy);
                    if (d2 < D2_THRESH)
                        csum += __expf(2.0f - sqrtf(d2) * (2.0f / DIST_THRESH)) - 1.0f;
                }
                if (csum > CURMAX_BREAK) sil = 1.0f;
            }
            if (s_cell[t] == cell) win = t;      // last valid t wins
        }
    }
    s_sil[wave][cl]  = sil;
    s_winp[wave][cl] = win;
    __syncthreads();

    // ---- phase 2: wave 0 combines chunks + computes the loss ----
    float contrib = 0.0f;
    if (wave == 0 && live) {
        float sl = fmaxf(fmaxf(s_sil[0][cl], s_sil[1][cl]),
                         fmaxf(s_sil[2][cl], s_sil[3][cl]));
        int wn = max(max(s_winp[0][cl], s_winp[1][cl]),
                     max(s_winp[2][cl], s_winp[3][cl]));
        const int h = cell / NW;
        const int w = cell - h * NW;
        const float* ob = output + (size_t)b * NCH * CELLS + cell;
        const float conf = sigmoidf_(ob[2*KPT * CELLS]);

        float cmask, tconf;
        if (wn >= 0) {
            cmask = OBJECT_SCALE;
            tconf = s_tconf[wn];
            #pragma unroll
            for (int k = 0; k < KPT; ++k) {
                // recover raw (xs,ys) from pixel preds: xo = px/SX - w
                float xo = pxs[k] * (1.0f/SX) - (float)w;
                float yo = pys[k] * (1.0f/SY) - (float)h;
                float2 txy = s_txy[wn][k];
                float dxv = xo - txy.x;
                float dyv = yo - txy.y;
                contrib += 0.5f * (dxv*dxv + dyv*dyv);   // COORD_SCALE = 1
            }
        } else {
            cmask = (sl > 0.0f) ? 0.0f : NOOBJECT_SCALE;
            tconf = 0.0f;
        }
        if (epoch_p[0] > PRETRAIN_EPOCHS) {
            float d = conf - tconf;
            contrib += 0.5f * cmask * d * d;
        }
    }

    // ---- wave-0 shuffle reduction + one atomic per block ----
    if (wave == 0) {
        #pragma unroll
        for (int off = 32; off > 0; off >>= 1)
            contrib += __shfl_down(contrib, off);
        if (cl == 0) atomicAdd(d_out, contrib);
    }
}

extern "C" void kernel_launch(void* const* d_in, const int* in_sizes, int n_in,
                              void* d_out, int out_size, void* d_ws, size_t ws_size,
                              hipStream_t stream) {
    const float* output = (const float*)d_in[0];
    const float* target = (const float*)d_in[1];
    const int*   epoch  = (const int*)d_in[2];
    float* out = (float*)d_out;

    zero_out_kernel<<<1, 1, 0, stream>>>(out);

    dim3 grid((CELLS + CPB - 1) / CPB, NB);
    region_loss_kernel<<<grid, 256, 0, stream>>>(output, target, epoch, out);
}

// Round 5
// 35.509 us; speedup vs baseline: 1.8606x; 1.0667x over previous
//
#include <hip/hip_runtime.h>
#include <math.h>

// ---- Problem constants (from reference) ----
#define KPT 9
#define NB 16
#define NH 76
#define NW 76
#define MAX_T 50
#define NCH 20                 // NA*(2K+1+NC) = 20
#define NUM_LABELS 21          // 2K+3
#define CELLS (NH*NW)          // 5776
#define IM_W 640.0f
#define IM_H 480.0f
#define SX (IM_W/(float)NW)    // px per cell, x
#define SY (IM_H/(float)NH)    // px per cell, y
#define DIST_THRESH 30.0f
#define D2_THRESH (DIST_THRESH*DIST_THRESH)
#define SIL_THRESH 0.6f
#define OBJECT_SCALE 5.0f
#define NOOBJECT_SCALE 0.1f
#define PRETRAIN_EPOCHS 15
// c = (exp(2*(1-d/30)) - 1) / (e^2 - 1), mean over K=9
#define E2M1 6.3890560989306495f          // e^2 - 1
#define CNORM (1.0f/(E2M1*9.0f))
// curconf > SIL_THRESH  <=>  raw csum > SIL_THRESH*(e^2-1)*9
#define CURMAX_BREAK (SIL_THRESH * E2M1 * 9.0f)
// csum <= cnt_close * (e^2-1); csum > BREAK requires cnt_close >= 6
#define CNT_MIN 6

#define TSPLIT 8               // target-loop split across 8 waves
#define CPB 64                 // cells per block (one per lane)
#define NTHREADS (TSPLIT*64)

__device__ __forceinline__ float sigmoidf_(float x) {
    return 1.0f / (1.0f + __expf(-x));
}

__global__ void zero_out_kernel(float* d_out) {
    d_out[0] = 0.0f;
}

__launch_bounds__(NTHREADS)
__global__ void region_loss_kernel(const float* __restrict__ output,
                                   const float* __restrict__ target,
                                   const int* __restrict__ epoch_p,
                                   float* __restrict__ d_out)
{
    const int tid  = threadIdx.x;
    const int wave = tid >> 6;       // 0..7 = target chunk
    const int cl   = tid & 63;       // cell within block
    const int b    = blockIdx.y;
    const int cell = blockIdx.x * CPB + cl;
    const bool live = (cell < CELLS);

    __shared__ float4 s_gt4[MAX_T][5];     // gt px coords packed: kpts (2j,2j+1); [4]=kpt8+pad
    __shared__ float2 s_txy[MAX_T][KPT];   // (tx,ty) residual targets
    __shared__ float  s_tconf[MAX_T];
    __shared__ int    s_nvalid;
    __shared__ int    s_win[CPB];          // per-cell winner t (max t wins) or -1
    __shared__ float  s_sil[TSPLIT][CPB];  // 1.0 if chunk silences cell

    const float* tgb = target + (size_t)b * MAX_T * NUM_LABELS;

    // ---- region A: validity prefix + winner-table init (wave 0) ----
    if (tid < 64) {
        float v1 = (tid < MAX_T) ? tgb[tid * NUM_LABELS + 1] : 1.0f;
        unsigned long long zm = __ballot(v1 == 0.0f);
        if (tid == 0) {
            int fz = (zm == 0ULL) ? MAX_T : (__ffsll((long long)zm) - 1);
            s_nvalid = fz < MAX_T ? fz : MAX_T;
        }
        s_win[tid] = -1;
    }
    __syncthreads();

    // ---- region B: per-target precompute into LDS (threads 0..49) ----
    if (tid < MAX_T) {
        const float* row = tgb + tid * NUM_LABELS;
        float gx0 = row[1] * (float)NW;
        float gy0 = row[2] * (float)NH;
        int gi0 = (int)gx0;               // truncation == astype(int32)
        int gj0 = (int)gy0;
        int cellt = gj0 * NW + gi0;
        int cellc = min(max(cellt, 0), CELLS - 1);
        int hc = cellc / NW, wc = cellc % NW;
        const float* ob = output + (size_t)b * NCH * CELLS + cellc;
        float* gdst = (float*)&s_gt4[tid][0];
        float csum = 0.0f;
        #pragma unroll
        for (int k = 0; k < KPT; ++k) {
            float gxk = row[1 + 2*k];
            float gyk = row[2 + 2*k];
            float gxp = gxk * IM_W;
            float gyp = gyk * IM_H;
            gdst[2*k]   = gxp;
            gdst[2*k+1] = gyp;
            s_txy[tid][k] = make_float2(gxk * (float)NW - (float)gi0,
                                        gyk * (float)NH - (float)gj0);
            float xo = ob[(2*k) * CELLS];
            float yo = ob[(2*k + 1) * CELLS];
            if (k == 0) { xo = sigmoidf_(xo); yo = sigmoidf_(yo); }
            float dx = gxp - (xo + (float)wc) * SX;
            float dy = gyp - (yo + (float)hc) * SY;
            float d2 = dx*dx + dy*dy;
            if (d2 < D2_THRESH) {
                csum += __expf(2.0f - sqrtf(d2) * (2.0f / DIST_THRESH)) - 1.0f;
            }
        }
        gdst[18] = 1e18f; gdst[19] = 1e18f;   // pad (never close)
        s_tconf[tid] = csum * CNORM;
        // winner scatter: last valid t wins == max t (atomicMax), mode='drop'
        bool scatter_ok = (gi0 >= 0 && gi0 < NW && gj0 >= 0 && gj0 < NH) &&
                          (tid < s_nvalid);
        int c = cellt - blockIdx.x * CPB;
        if (scatter_ok && c >= 0 && c < CPB) atomicMax(&s_win[c], tid);
    }
    __syncthreads();

    const int nv = s_nvalid;

    // ---- phase 1: each wave scans its strided target chunk (branchless) ----
    float pxs[KPT], pys[KPT];
    float sil = 0.0f;                // cell silenced (curconf > SIL_THRESH)?
    if (live) {
        const int h = cell / NW;
        const int w = cell - h * NW;
        const float* ob = output + (size_t)b * NCH * CELLS + cell;
        #pragma unroll
        for (int k = 0; k < KPT; ++k) {
            float xo = ob[(2*k) * CELLS];
            float yo = ob[(2*k + 1) * CELLS];
            if (k == 0) { xo = sigmoidf_(xo); yo = sigmoidf_(yo); }
            pxs[k] = (xo + (float)w) * SX;
            pys[k] = (yo + (float)h) * SY;
        }
        for (int t = wave; t < nv; t += TSPLIT) {
            float4 q0 = s_gt4[t][0];   // broadcast ds_read_b128, no conflict
            float4 q1 = s_gt4[t][1];
            float4 q2 = s_gt4[t][2];
            float4 q3 = s_gt4[t][3];
            float4 q4 = s_gt4[t][4];
            int cnt = 0;
            #define KP(gx, gy, k) { \
                float dx = (gx) - pxs[k]; \
                float dy = (gy) - pys[k]; \
                float d2 = __builtin_fmaf(dx, dx, dy*dy); \
                cnt += (d2 < D2_THRESH) ? 1 : 0; }
            KP(q0.x, q0.y, 0) KP(q0.z, q0.w, 1)
            KP(q1.x, q1.y, 2) KP(q1.z, q1.w, 3)
            KP(q2.x, q2.y, 4) KP(q2.z, q2.w, 5)
            KP(q3.x, q3.y, 6) KP(q3.z, q3.w, 7)
            KP(q4.x, q4.y, 8)
            #undef KP
            // csum can exceed CURMAX_BREAK only if >= CNT_MIN kpts close.
            // Exec-masked rare path (P ~ 1e-10 per pair): exact evaluation.
            if (cnt >= CNT_MIN) {
                const float* gq = (const float*)&s_gt4[t][0];
                float csum = 0.0f;
                #pragma unroll
                for (int k = 0; k < KPT; ++k) {
                    float dx = gq[2*k]   - pxs[k];
                    float dy = gq[2*k+1] - pys[k];
                    float d2 = __builtin_fmaf(dx, dx, dy*dy);
                    if (d2 < D2_THRESH)
                        csum += __expf(2.0f - sqrtf(d2) * (2.0f / DIST_THRESH)) - 1.0f;
                }
                if (csum > CURMAX_BREAK) sil = 1.0f;
            }
        }
    }
    s_sil[wave][cl] = sil;
    __syncthreads();

    // ---- phase 2: wave 0 combines chunks + computes the loss ----
    float contrib = 0.0f;
    if (wave == 0 && live) {
        float sl = 0.0f;
        #pragma unroll
        for (int wv = 0; wv < TSPLIT; ++wv) sl = fmaxf(sl, s_sil[wv][cl]);
        const int wn = s_win[cl];
        const int h = cell / NW;
        const int w = cell - h * NW;
        const float* ob = output + (size_t)b * NCH * CELLS + cell;
        const float conf = sigmoidf_(ob[2*KPT * CELLS]);

        float cmask, tconf;
        if (wn >= 0) {
            cmask = OBJECT_SCALE;
            tconf = s_tconf[wn];
            #pragma unroll
            for (int k = 0; k < KPT; ++k) {
                // recover raw (xs,ys) from pixel preds: xo = px/SX - w
                float xo = pxs[k] * (1.0f/SX) - (float)w;
                float yo = pys[k] * (1.0f/SY) - (float)h;
                float2 txy = s_txy[wn][k];
                float dxv = xo - txy.x;
                float dyv = yo - txy.y;
                contrib += 0.5f * (dxv*dxv + dyv*dyv);   // COORD_SCALE = 1
            }
        } else {
            cmask = (sl > 0.0f) ? 0.0f : NOOBJECT_SCALE;
            tconf = 0.0f;
        }
        if (epoch_p[0] > PRETRAIN_EPOCHS) {
            float d = conf - tconf;
            contrib += 0.5f * cmask * d * d;
        }
    }

    // ---- wave-0 shuffle reduction + one atomic per block ----
    if (wave == 0) {
        #pragma unroll
        for (int off = 32; off > 0; off >>= 1)
            contrib += __shfl_down(contrib, off);
        if (cl == 0) atomicAdd(d_out, contrib);
    }
}

extern "C" void kernel_launch(void* const* d_in, const int* in_sizes, int n_in,
                              void* d_out, int out_size, void* d_ws, size_t ws_size,
                              hipStream_t stream) {
    const float* output = (const float*)d_in[0];
    const float* target = (const float*)d_in[1];
    const int*   epoch  = (const int*)d_in[2];
    float* out = (float*)d_out;

    zero_out_kernel<<<1, 1, 0, stream>>>(out);

    dim3 grid((CELLS + CPB - 1) / CPB, NB);
    region_loss_kernel<<<grid, NTHREADS, 0, stream>>>(output, target, epoch, out);
}